// Round 9
// baseline (820.094 us; speedup 1.0000x reference)
//
#include <hip/hip_runtime.h>
#include <hip/hip_bf16.h>

typedef __hip_bfloat16 bf16;
typedef __attribute__((ext_vector_type(8))) short short8;
typedef __attribute__((ext_vector_type(4))) float floatx4;

#define NN     131072
#define NEDGE  1048576
#define BG     1024
#define LAYERS 3
#define TG     8      // graphs per tail block
#define ZTOTM  (768 + 6*BG*64)   // stats3 (2x3x128) + pooled3 (2x3xBGx64)

// bf16 split helpers (RNE)
__device__ __forceinline__ short f2bf_s(float f){
    union { float f; unsigned u; } x; x.f = f;
    unsigned r = x.u + 0x7fffu + ((x.u >> 16) & 1u);
    return (short)(r >> 16);
}
__device__ __forceinline__ float bf2f_s(short s){
    union { unsigned u; float f; } x; x.u = ((unsigned)(unsigned short)s) << 16;
    return x.f;
}
__device__ __forceinline__ void acc4(const unsigned short* p,
                                     float& a0, float& a1, float& a2, float& a3){
    ushort4 u = *(const ushort4*)p;
    a0 += bf2f_s((short)u.x); a1 += bf2f_s((short)u.y);
    a2 += bf2f_s((short)u.z); a3 += bf2f_s((short)u.w);
}

// ------------------------------------------------------------------
// Weight prep (once/launch): Wt[n][k] = W[k][n], split bf16 hi/lo.
// ------------------------------------------------------------------
__global__ __launch_bounds__(256) void k_wprep(
    const float* __restrict__ gw1, const float* __restrict__ gw2,
    const float* __restrict__ iw,
    short* __restrict__ w1h, short* __restrict__ w1l,
    short* __restrict__ w2h, short* __restrict__ w2l,
    short* __restrict__ wih, short* __restrict__ wil)
{
    int i = blockIdx.x*256 + threadIdx.x;
    if (i >= 3*LAYERS*4096) return;
    int msel = i / (LAYERS*4096);
    int rem  = i % (LAYERS*4096);
    int l = rem >> 12, idx = rem & 4095;
    int n = idx >> 6, k = idx & 63;
    const float* src = (msel==0) ? gw1 : (msel==1) ? gw2 : iw;
    float v = src[l*4096 + k*64 + n];
    short hi = f2bf_s(v);
    short lo = f2bf_s(v - bf2f_s(hi));
    short* dh = (msel==0) ? w1h : (msel==1) ? w2h : wih;
    short* dl = (msel==0) ? w1l : (msel==1) ? w2l : wil;
    dh[rem] = hi;
    dl[rem] = lo;
}

// ------------------------------------------------------------------
// fp32 -> bf16 shadow of BOTH sides' node features + zero cnt/zbuf.
// ------------------------------------------------------------------
__global__ __launch_bounds__(256) void k_cvtM(const float* __restrict__ qx,
                                              const float* __restrict__ cx,
                                              bf16* __restrict__ xh,
                                              int* __restrict__ cnt,
                                              float* __restrict__ zbuf)
{
    int i = blockIdx.x*256 + threadIdx.x;   // 16384 blocks -> 2*NN*16 quads
    float4 v = (i < NN*16) ? ((const float4*)qx)[i]
                           : ((const float4*)cx)[i - NN*16];
    short4 o;
    o.x = f2bf_s(v.x); o.y = f2bf_s(v.y);
    o.z = f2bf_s(v.z); o.w = f2bf_s(v.w);
    ((short4*)xh)[i] = o;
    if (i < 2*NN)   cnt[i]  = 0;
    if (i < ZTOTM)  zbuf[i] = 0.f;
}

// ------------------------------------------------------------------
// CSR build over combined 2N-node / 2M-edge graph (side-1 +NN).
// ------------------------------------------------------------------
__global__ __launch_bounds__(256) void k_histM(const int* __restrict__ qei,
                                               const int* __restrict__ cei,
                                               int* __restrict__ cnt,
                                               int* __restrict__ rank)
{
    int e = blockIdx.x*256 + threadIdx.x;   // 8192 blocks -> 2M edges
    int side = e >> 20;                     // NEDGE = 1<<20
    int el = e & (NEDGE-1);
    const int* ei = side ? cei : qei;
    rank[e] = atomicAdd(cnt + ei[NEDGE + el] + side*NN, 1);
}

__global__ __launch_bounds__(256) void k_scan1M(const int* __restrict__ cnt,
    int* __restrict__ rowptr, int* __restrict__ bsum)
{
    __shared__ int sd[256];
    int t = threadIdx.x;
    int base = blockIdx.x*1024 + t*4;       // grid 256 -> 2NN entries
    int c0 = cnt[base], c1 = cnt[base+1], c2 = cnt[base+2], c3 = cnt[base+3];
    int tsum = c0 + c1 + c2 + c3;
    sd[t] = tsum;
    __syncthreads();
    for (int off = 1; off < 256; off <<= 1) {
        int v = (t >= off) ? sd[t-off] : 0;
        __syncthreads();
        sd[t] += v;
        __syncthreads();
    }
    int excl = sd[t] - tsum;
    rowptr[base]   = excl;
    rowptr[base+1] = excl + c0;
    rowptr[base+2] = excl + c0 + c1;
    rowptr[base+3] = excl + c0 + c1 + c2;
    if (t == 255) bsum[blockIdx.x] = sd[255];
}

__global__ __launch_bounds__(256) void k_scan2M(const int* __restrict__ bsum,
    int* __restrict__ boff, int* __restrict__ rowptr)
{
    __shared__ int sd[256];
    int t = threadIdx.x;
    int v0 = bsum[t];
    sd[t] = v0;
    __syncthreads();
    for (int off = 1; off < 256; off <<= 1) {
        int v = (t >= off) ? sd[t-off] : 0;
        __syncthreads();
        sd[t] += v;
        __syncthreads();
    }
    boff[t] = sd[t] - v0;
    if (t == 0) rowptr[2*NN] = 2*NEDGE;
}

__global__ __launch_bounds__(256) void k_scan3M(int* __restrict__ rowptr,
    const int* __restrict__ boff)
{
    int i = blockIdx.x*256 + threadIdx.x;   // grid 1024 -> 2NN
    rowptr[i] += boff[i >> 10];
}

__global__ __launch_bounds__(256) void k_fillM(const int* __restrict__ qei,
    const int* __restrict__ cei,
    const int* __restrict__ rowptr, const int* __restrict__ rank,
    int* __restrict__ col)
{
    int e = blockIdx.x*256 + threadIdx.x;
    int side = e >> 20;
    int el = e & (NEDGE-1);
    const int* ei = side ? cei : qei;
    int s = ei[el] + side*NN;
    int d = ei[NEDGE + el] + side*NN;
    col[rowptr[d] + rank[e]] = s;
}

// ------------------------------------------------------------------
// FUSED aggregate + GIN MLP, both sides (grid 2048, side = bid>>10).
// NEW: when wihp != null, also computes the PREVIOUS layer's inner
// MLP + graph pool for its 32 nodes (A-frags read direct from xh,
// which phase 1 re-reads moments later -> cache-warm).
// ------------------------------------------------------------------
__global__ __launch_bounds__(256) void k_agg_ginM(
    const bf16* __restrict__ xh,
    const int* __restrict__ rowptr, const int* __restrict__ col,
    const float* __restrict__ epsp,
    const short* __restrict__ w1h, const short* __restrict__ w1l,
    const float* __restrict__ b1,
    const short* __restrict__ w2h, const short* __restrict__ w2l,
    const float* __restrict__ b2,
    unsigned short* __restrict__ bigh, float* __restrict__ stats,
    const short* __restrict__ wihp, const short* __restrict__ wilp,
    const float* __restrict__ bip,
    const int* __restrict__ gidx_q, const int* __restrict__ gidx_c,
    float* __restrict__ pool_q, float* __restrict__ pool_c)
{
    __shared__ __align__(16) char buf[4][9472];
    __shared__ float red[2][4][64];
    int bid = blockIdx.x;
    int side = bid >> 10;
    int tid = threadIdx.x, wv = tid >> 6, lane = tid & 63;
    int q = lane >> 4, m = lane & 15;
    int nb = bid*128 + wv*32;          // global node base
    short* Sh = (short*)buf[wv];
    short* Sl = Sh + 2304;      // 32*72
    float ep = 1.0f + *epsp;
    const short* xs = (const short*)xh;

    // prefetch A-frags of own x rows for the relocated inner MLP
    short8 A3[2][2];
    if (wihp) {
        #pragma unroll
        for (int mc=0; mc<2; mc++)
          #pragma unroll
          for (int kc=0; kc<2; kc++)
            A3[mc][kc] = *(const short8*)(xs + (((size_t)(nb + mc*16 + m)) << 6)
                                             + kc*32 + q*8);
    }

    // ---- Phase 1: group-per-node gather (proven geometry, unchanged) ----
    int gv = rowptr[nb + (lane < 33 ? lane : 32)];
    int fo = m * 4;
    const unsigned short* xt = (const unsigned short*)xh;

    for (int i = 0; i < 8; i++) {
        int row = i*4 + q;
        int rs = __shfl(gv, row, 64);
        int re = __shfl(gv, row+1, 64);
        float a0=0.f,a1=0.f,a2=0.f,a3=0.f;
        float e0=0.f,e1=0.f,e2=0.f,e3=0.f;
        float g0=0.f,g1=0.f,g2=0.f,g3=0.f;
        float h0=0.f,h1=0.f,h2=0.f,h3=0.f;
        int r = rs;
        for (; r + 4 <= re; r += 4) {
            int ca = col[r], cb = col[r+1], cc = col[r+2], cd = col[r+3];
            acc4(xt + (((size_t)ca) << 6) + fo, a0,a1,a2,a3);
            acc4(xt + (((size_t)cb) << 6) + fo, e0,e1,e2,e3);
            acc4(xt + (((size_t)cc) << 6) + fo, g0,g1,g2,g3);
            acc4(xt + (((size_t)cd) << 6) + fo, h0,h1,h2,h3);
        }
        for (; r < re; r++)
            acc4(xt + (((size_t)col[r]) << 6) + fo, a0,a1,a2,a3);
        a0 += e0 + g0 + h0;
        a1 += e1 + g1 + h1;
        a2 += e2 + g2 + h2;
        a3 += e3 + g3 + h3;
        ushort4 sv = *(const ushort4*)(xt + (((size_t)(nb+row)) << 6) + fo);
        a0 = fmaf(ep, bf2f_s((short)sv.x), a0);
        a1 = fmaf(ep, bf2f_s((short)sv.y), a1);
        a2 = fmaf(ep, bf2f_s((short)sv.z), a2);
        a3 = fmaf(ep, bf2f_s((short)sv.w), a3);
        short4 hh, ll;
        hh.x = f2bf_s(a0); ll.x = f2bf_s(a0 - bf2f_s(hh.x));
        hh.y = f2bf_s(a1); ll.y = f2bf_s(a1 - bf2f_s(hh.y));
        hh.z = f2bf_s(a2); ll.z = f2bf_s(a2 - bf2f_s(hh.z));
        hh.w = f2bf_s(a3); ll.w = f2bf_s(a3 - bf2f_s(hh.w));
        *(short4*)(Sh + row*72 + fo) = hh;
        *(short4*)(Sl + row*72 + fo) = ll;
    }
    __syncthreads();

    // ---- Phase 2: GEMM1 ----
    short8 Ah[2][2], Al[2][2];
    #pragma unroll
    for (int mc=0; mc<2; mc++)
      #pragma unroll
      for (int kc=0; kc<2; kc++){
        Ah[mc][kc] = *(const short8*)(Sh + (mc*16+m)*72 + kc*32 + q*8);
        Al[mc][kc] = *(const short8*)(Sl + (mc*16+m)*72 + kc*32 + q*8);
      }
    floatx4 acc[2][4];
    #pragma unroll
    for (int mc=0;mc<2;mc++)
      #pragma unroll
      for (int nc=0;nc<4;nc++) acc[mc][nc] = (floatx4){0.f,0.f,0.f,0.f};
    #pragma unroll
    for (int nc=0;nc<4;nc++){
      #pragma unroll
      for (int kc=0;kc<2;kc++){
        short8 bh = *(const short8*)(w1h + (nc*16+m)*64 + kc*32 + q*8);
        short8 bl = *(const short8*)(w1l + (nc*16+m)*64 + kc*32 + q*8);
        #pragma unroll
        for (int mc=0;mc<2;mc++){
          acc[mc][nc] = __builtin_amdgcn_mfma_f32_16x16x32_bf16(Ah[mc][kc], bh, acc[mc][nc],0,0,0);
          acc[mc][nc] = __builtin_amdgcn_mfma_f32_16x16x32_bf16(Al[mc][kc], bh, acc[mc][nc],0,0,0);
          acc[mc][nc] = __builtin_amdgcn_mfma_f32_16x16x32_bf16(Ah[mc][kc], bl, acc[mc][nc],0,0,0);
        }
      }
    }

    // epilogue 1: bias + relu, split back into LDS
    #pragma unroll
    for (int nc=0;nc<4;nc++){
      float bia = b1[nc*16+m];
      #pragma unroll
      for (int mc=0;mc<2;mc++)
        #pragma unroll
        for (int r=0;r<4;r++){
          float v = fmaxf(acc[mc][nc][r] + bia, 0.f);
          int row = mc*16 + q*4 + r, cl = nc*16 + m;
          short hb = f2bf_s(v);
          Sh[row*72+cl] = hb;
          Sl[row*72+cl] = f2bf_s(v - bf2f_s(hb));
        }
    }
    __syncthreads();

    // GEMM2
    short8 A2h[2][2], A2l[2][2];
    #pragma unroll
    for (int mc=0; mc<2; mc++)
      #pragma unroll
      for (int kc=0; kc<2; kc++){
        A2h[mc][kc] = *(const short8*)(Sh + (mc*16+m)*72 + kc*32 + q*8);
        A2l[mc][kc] = *(const short8*)(Sl + (mc*16+m)*72 + kc*32 + q*8);
      }
    floatx4 acc2[2][4];
    #pragma unroll
    for (int mc=0;mc<2;mc++)
      #pragma unroll
      for (int nc=0;nc<4;nc++) acc2[mc][nc] = (floatx4){0.f,0.f,0.f,0.f};
    #pragma unroll
    for (int nc=0;nc<4;nc++){
      #pragma unroll
      for (int kc=0;kc<2;kc++){
        short8 bh = *(const short8*)(w2h + (nc*16+m)*64 + kc*32 + q*8);
        short8 bl = *(const short8*)(w2l + (nc*16+m)*64 + kc*32 + q*8);
        #pragma unroll
        for (int mc=0;mc<2;mc++){
          acc2[mc][nc] = __builtin_amdgcn_mfma_f32_16x16x32_bf16(A2h[mc][kc], bh, acc2[mc][nc],0,0,0);
          acc2[mc][nc] = __builtin_amdgcn_mfma_f32_16x16x32_bf16(A2l[mc][kc], bh, acc2[mc][nc],0,0,0);
          acc2[mc][nc] = __builtin_amdgcn_mfma_f32_16x16x32_bf16(A2h[mc][kc], bl, acc2[mc][nc],0,0,0);
        }
      }
    }

    // epilogue 2: bias, store h2 (bf16), BN stats per side (fp32-exact)
    #pragma unroll
    for (int nc=0;nc<4;nc++){
      float bia = b2[nc*16+m];
      float s = 0.f, s2 = 0.f;
      #pragma unroll
      for (int mc=0;mc<2;mc++)
        #pragma unroll
        for (int r=0;r<4;r++){
          float v = acc2[mc][nc][r] + bia;
          bigh[(((size_t)(nb + mc*16 + q*4 + r)) << 6) + nc*16 + m] =
              (unsigned short)f2bf_s(v);
          s += v; s2 = fmaf(v, v, s2);
        }
      s  += __shfl_xor(s, 16, 64);  s  += __shfl_xor(s, 32, 64);
      s2 += __shfl_xor(s2,16, 64);  s2 += __shfl_xor(s2,32, 64);
      if (q == 0){ red[0][wv][nc*16+m] = s; red[1][wv][nc*16+m] = s2; }
    }
    __syncthreads();
    if (tid < 128){
      int which = tid >> 6, c = tid & 63;
      float a = red[which][0][c]+red[which][1][c]+red[which][2][c]+red[which][3][c];
      unsafeAtomicAdd(stats + side*128 + which*64 + c, a);
    }

    // ---- relocated inner MLP + pool of PREVIOUS layer ----
    if (wihp) {
        floatx4 acc3[2][4];
        #pragma unroll
        for (int mc=0;mc<2;mc++)
          #pragma unroll
          for (int nc=0;nc<4;nc++) acc3[mc][nc] = (floatx4){0.f,0.f,0.f,0.f};
        #pragma unroll
        for (int nc=0;nc<4;nc++){
          #pragma unroll
          for (int kc=0;kc<2;kc++){
            short8 bh = *(const short8*)(wihp + (nc*16+m)*64 + kc*32 + q*8);
            short8 bl = *(const short8*)(wilp + (nc*16+m)*64 + kc*32 + q*8);
            #pragma unroll
            for (int mc=0;mc<2;mc++){
              acc3[mc][nc] = __builtin_amdgcn_mfma_f32_16x16x32_bf16(A3[mc][kc], bh, acc3[mc][nc],0,0,0);
              acc3[mc][nc] = __builtin_amdgcn_mfma_f32_16x16x32_bf16(A3[mc][kc], bl, acc3[mc][nc],0,0,0);
            }
          }
        }
        __syncthreads();   // prior phases done; repurpose buf per-wave
        float* P = (float*)buf[wv];
        #pragma unroll
        for (int nc=0;nc<4;nc++){
          float bia = bip[nc*16+m];
          #pragma unroll
          for (int mc=0;mc<2;mc++)
            #pragma unroll
            for (int r=0;r<4;r++){
              float v = fmaxf(acc3[mc][nc][r] + bia, 0.f);
              P[(mc*16 + q*4 + r)*66 + nc*16 + m] = v;
            }
        }
        __syncthreads();

        const int* gidx = side ? gidx_c : gidx_q;
        float* pooled   = side ? pool_c : pool_q;
        int ln = nb - side*NN;
        int gv2 = (lane < 32) ? gidx[ln + lane] : 0;
        int cur = __shfl(gv2, 0, 64);
        float a = 0.f;
        for (int rr = 0; rr < 32; rr++){
            int g = __shfl(gv2, rr, 64);
            if (g != cur){
                unsafeAtomicAdd(pooled + (size_t)cur*64 + lane, a);
                a = 0.f; cur = g;
            }
            a += P[rr*66 + lane];
        }
        unsafeAtomicAdd(pooled + (size_t)cur*64 + lane, a);
    }
}

// ------------------------------------------------------------------
// NEW: pure BN-apply (bigh -> xh), elementwise, high occupancy.
// Blocks <512 optionally fold the previous layer's outer MLP.
// ------------------------------------------------------------------
__global__ __launch_bounds__(256) void k_bn_apply(
    const unsigned short* __restrict__ bigh, const float* __restrict__ stats,
    const float* __restrict__ gam, const float* __restrict__ bet,
    bf16* __restrict__ xh,
    const float* __restrict__ pprev_q, const float* __restrict__ pprev_c,
    const float* __restrict__ owp, const float* __restrict__ obp,
    float* __restrict__ qf, float* __restrict__ cf, int coffp)
{
    __shared__ float scs[128], shs[128];
    int t = threadIdx.x;
    if (t < 128) {
        int side = t >> 6, c = t & 63;
        const float* st = stats + side*128;
        float mu  = st[c]    * (1.0f/NN);
        float ex2 = st[64+c] * (1.0f/NN);
        float var = ex2 - mu*mu;
        float sc  = gam[c] * rsqrtf(var + 1e-5f);
        scs[t] = sc;
        shs[t] = bet[c] - mu*sc;
    }
    if (owp && blockIdx.x < 512) {
        int side = blockIdx.x >> 8;
        int g = (blockIdx.x & 255)*256 + t;
        int bb = g >> 6, j = g & 63;
        const float* pr = (side ? pprev_c : pprev_q) + (size_t)bb*64;
        float a = obp[j];
        for (int k = 0; k < 64; k++) a = fmaf(pr[k], owp[k*64 + j], a);
        (side ? cf : qf)[bb*192 + coffp + j] = fmaxf(a, 0.f);
    }
    __syncthreads();

    int i = blockIdx.x*256 + t;           // 16384 blocks, quad per thread
    ushort4 u = ((const ushort4*)bigh)[i];
    int e = i << 2;
    int base = ((e >> 6) >> 17)*64 + (e & 63);   // side*64 + col
    short4 o;
    float v0 = fmaxf(fmaf(bf2f_s((short)u.x), scs[base],   shs[base]),   0.f);
    float v1 = fmaxf(fmaf(bf2f_s((short)u.y), scs[base+1], shs[base+1]), 0.f);
    float v2 = fmaxf(fmaf(bf2f_s((short)u.z), scs[base+2], shs[base+2]), 0.f);
    float v3 = fmaxf(fmaf(bf2f_s((short)u.w), scs[base+3], shs[base+3]), 0.f);
    o.x = f2bf_s(v0); o.y = f2bf_s(v1); o.z = f2bf_s(v2); o.w = f2bf_s(v3);
    ((short4*)xh)[i] = o;
}

// ------------------------------------------------------------------
// FULL bn_inner: used only for the LAST layer (pool_2 has no
// following agg). Adds outer_1 fold (pooled_1 from agg(2)).
// ------------------------------------------------------------------
__global__ __launch_bounds__(256) void k_bn_innerM(
    const unsigned short* __restrict__ bigh, const float* __restrict__ stats,
    const float* __restrict__ gam, const float* __restrict__ bet,
    const short* __restrict__ wih, const short* __restrict__ wil,
    const float* __restrict__ bi,
    bf16* __restrict__ xh,
    const int* __restrict__ gidx_q, const int* __restrict__ gidx_c,
    float* __restrict__ pooled_q, float* __restrict__ pooled_c,
    const float* __restrict__ pprev_q, const float* __restrict__ pprev_c,
    const float* __restrict__ owp, const float* __restrict__ obp,
    float* __restrict__ qf, float* __restrict__ cf, int coffp)
{
    __shared__ __align__(16) char buf[4][9472];
    int bid = blockIdx.x;
    int side = bid >> 10;
    int lb = bid & 1023;
    int tid = threadIdx.x, wv = tid >> 6, lane = tid & 63;
    int q = lane >> 4, m = lane & 15;
    int nb = bid*128 + wv*32;          // global
    short* Sh = (short*)buf[wv];
    short* Sl = Sh + 2304;

    if (owp && lb < 256) {
        int g = lb*256 + tid;
        int bb = g >> 6, j = g & 63;
        const float* pr = (side ? pprev_c : pprev_q) + (size_t)bb*64;
        float a = obp[j];
        for (int k = 0; k < 64; k++) a = fmaf(pr[k], owp[k*64 + j], a);
        (side ? cf : qf)[bb*192 + coffp + j] = fmaxf(a, 0.f);
    }

    const float* st = stats + side*128;
    float mu  = st[lane]    * (1.0f/NN);
    float ex2 = st[64+lane] * (1.0f/NN);
    float var = ex2 - mu*mu;
    float sc  = gam[lane] * rsqrtf(var + 1e-5f);
    float sh  = bet[lane] - mu*sc;

    for (int rr = 0; rr < 32; rr++){
        float v = bf2f_s((short)bigh[(((size_t)(nb+rr)) << 6) + lane]);
        v = fmaxf(fmaf(v, sc, sh), 0.f);
        xh[(((size_t)(nb+rr)) << 6) + lane] = __float2bfloat16(v);
        short hb = f2bf_s(v);
        Sh[rr*72 + lane] = hb;
        Sl[rr*72 + lane] = f2bf_s(v - bf2f_s(hb));
    }
    __syncthreads();

    short8 A2h[2][2], A2l[2][2];
    #pragma unroll
    for (int mc=0; mc<2; mc++)
      #pragma unroll
      for (int kc=0; kc<2; kc++){
        A2h[mc][kc] = *(const short8*)(Sh + (mc*16+m)*72 + kc*32 + q*8);
        A2l[mc][kc] = *(const short8*)(Sl + (mc*16+m)*72 + kc*32 + q*8);
      }
    floatx4 acc[2][4];
    #pragma unroll
    for (int mc=0;mc<2;mc++)
      #pragma unroll
      for (int nc=0;nc<4;nc++) acc[mc][nc] = (floatx4){0.f,0.f,0.f,0.f};
    #pragma unroll
    for (int nc=0;nc<4;nc++){
      #pragma unroll
      for (int kc=0;kc<2;kc++){
        short8 bh = *(const short8*)(wih + (nc*16+m)*64 + kc*32 + q*8);
        short8 bl = *(const short8*)(wil + (nc*16+m)*64 + kc*32 + q*8);
        #pragma unroll
        for (int mc=0;mc<2;mc++){
          acc[mc][nc] = __builtin_amdgcn_mfma_f32_16x16x32_bf16(A2h[mc][kc], bh, acc[mc][nc],0,0,0);
          acc[mc][nc] = __builtin_amdgcn_mfma_f32_16x16x32_bf16(A2l[mc][kc], bh, acc[mc][nc],0,0,0);
          acc[mc][nc] = __builtin_amdgcn_mfma_f32_16x16x32_bf16(A2h[mc][kc], bl, acc[mc][nc],0,0,0);
        }
      }
    }
    __syncthreads();

    float* P = (float*)buf[wv];
    #pragma unroll
    for (int nc=0;nc<4;nc++){
      float bia = bi[nc*16+m];
      #pragma unroll
      for (int mc=0;mc<2;mc++)
        #pragma unroll
        for (int r=0;r<4;r++){
          float v = fmaxf(acc[mc][nc][r] + bia, 0.f);
          P[(mc*16 + q*4 + r)*66 + nc*16 + m] = v;
        }
    }
    __syncthreads();

    const int* gidx = side ? gidx_c : gidx_q;
    float* pooled   = side ? pooled_c : pooled_q;
    int ln = nb - side*NN;
    int gv = (lane < 32) ? gidx[ln + lane] : 0;
    int cur = __shfl(gv, 0, 64);
    float a = 0.f;
    for (int rr = 0; rr < 32; rr++){
        int g = __shfl(gv, rr, 64);
        if (g != cur){
            unsafeAtomicAdd(pooled + (size_t)cur*64 + lane, a);
            a = 0.f; cur = g;
        }
        a += P[rr*66 + lane];
    }
    unsafeAtomicAdd(pooled + (size_t)cur*64 + lane, a);
}

// ------------------------------------------------------------------
// Tail: TG graphs per block; BOTH sides' layer-2 outer inline.
// ------------------------------------------------------------------
__global__ __launch_bounds__(256) void k_tailM(
    const float* __restrict__ qf, const float* __restrict__ cf,
    const float* __restrict__ pooled_q2, const float* __restrict__ pooled_c2,
    const float* __restrict__ ow2, const float* __restrict__ ob2,
    const float* __restrict__ cw1, const float* __restrict__ cb1,
    const float* __restrict__ cw2, const float* __restrict__ cb2,
    const float* __restrict__ sw1, const float* __restrict__ sb1,
    const float* __restrict__ sw2, const float* __restrict__ sb2,
    const float* __restrict__ nw,  const float* __restrict__ nwb,
    const float* __restrict__ nb,
    const float* __restrict__ mw1, const float* __restrict__ mb1,
    const float* __restrict__ mw2, const float* __restrict__ mb2,
    const float* __restrict__ alpha, const float* __restrict__ beta,
    float* __restrict__ out)
{
    __shared__ float cws[192*96];
    __shared__ float diff[TG][192];
    __shared__ float e1s[TG][64], e2s[TG][64];
    __shared__ float h1s[TG][96], h2s[TG][96];
    __shared__ float s1s[TG][16], s2s[TG][16], srep[TG][16];
    __shared__ float red[16][16][TG];

    int t = threadIdx.x;
    int b0 = blockIdx.x * TG;

    {
        int b = t >> 5, o = (t & 31) * 2;
        const float* prq = pooled_q2 + (size_t)(b0 + b)*64;
        const float* prc = pooled_c2 + (size_t)(b0 + b)*64;
        float q0 = ob2[o], q1 = ob2[o+1];
        float c0 = ob2[o], c1 = ob2[o+1];
        for (int k = 0; k < 64; k++) {
            float w0 = ow2[k*64 + o], w1 = ow2[k*64 + o + 1];
            float pq = prq[k], pc = prc[k];
            q0 = fmaf(pq, w0, q0); q1 = fmaf(pq, w1, q1);
            c0 = fmaf(pc, w0, c0); c1 = fmaf(pc, w1, c1);
        }
        e1s[b][o]   = fmaxf(q0, 0.f);
        e1s[b][o+1] = fmaxf(q1, 0.f);
        e2s[b][o]   = fmaxf(c0, 0.f);
        e2s[b][o+1] = fmaxf(c1, 0.f);
    }
    for (int i = t; i < 192*96; i += 256) cws[i] = cw1[i];
    __syncthreads();

    for (int i = t; i < TG*192; i += 256) {
        int b = i / 192, f = i % 192;
        float qv = (f < 128) ? qf[(b0+b)*192 + f] : e1s[b][f-128];
        float cv = (f < 128) ? cf[(b0+b)*192 + f] : e2s[b][f-128];
        float d = qv - cv;
        diff[b][f] = __expf(-d*d);
    }
    __syncthreads();

    {
        int b = t >> 5, o = (t & 31) * 3;
        float a0 = cb1[o], a1 = cb1[o+1], a2 = cb1[o+2];
        for (int f = 0; f < 192; f++) {
            float d = diff[b][f];
            const float* w = cws + f*96 + o;
            a0 = fmaf(d, w[0], a0);
            a1 = fmaf(d, w[1], a1);
            a2 = fmaf(d, w[2], a2);
        }
        h1s[b][o] = fmaxf(a0, 0.f);
        h1s[b][o+1] = fmaxf(a1, 0.f);
        h1s[b][o+2] = fmaxf(a2, 0.f);
    }
    __syncthreads();
    for (int i = t; i < 96*96; i += 256) cws[i] = cw2[i];
    __syncthreads();
    {
        int b = t >> 5, o = (t & 31) * 3;
        float a0 = cb2[o], a1 = cb2[o+1], a2 = cb2[o+2];
        for (int f = 0; f < 96; f++) {
            float d = h1s[b][f];
            const float* w = cws + f*96 + o;
            a0 = fmaf(d, w[0], a0);
            a1 = fmaf(d, w[1], a1);
            a2 = fmaf(d, w[2], a2);
        }
        h2s[b][o] = tanhf(a0);
        h2s[b][o+1] = tanhf(a1);
        h2s[b][o+2] = tanhf(a2);
    }
    __syncthreads();
    if (t < TG*16) {
        int b = t >> 4, o = t & 15;
        float a = sb1[o];
        for (int f = 0; f < 96; f++) a = fmaf(h2s[b][f], sw1[f*16+o], a);
        s1s[b][o] = fmaxf(a, 0.f);
    }

    {
        int tt = t & 15, gq = t >> 4;
        int g0 = gq * 4;
        int lane = t & 63;
        float e1v[TG];
        #pragma unroll
        for (int b = 0; b < TG; b++) e1v[b] = e1s[b][lane];
        float v0[TG], v1[TG], v2[TG], v3[TG];
        #pragma unroll
        for (int b = 0; b < TG; b++) { v0[b]=0.f; v1[b]=0.f; v2[b]=0.f; v3[b]=0.f; }
        for (int f = 0; f < 64; f++) {
            const float* wp = nw + ((size_t)f*64 + g0)*16 + tt;
            float w0 = wp[0], w1 = wp[16], w2 = wp[32], w3 = wp[48];
            #pragma unroll
            for (int b = 0; b < TG; b++) {
                float e = __shfl(e1v[b], f, 64);
                v0[b] = fmaf(e, w0, v0[b]);
                v1[b] = fmaf(e, w1, v1[b]);
                v2[b] = fmaf(e, w2, v2[b]);
                v3[b] = fmaf(e, w3, v3[b]);
            }
        }
        #pragma unroll
        for (int b = 0; b < TG; b++) {
            float p = v0[b]*e2s[b][g0] + v1[b]*e2s[b][g0+1]
                    + v2[b]*e2s[b][g0+2] + v3[b]*e2s[b][g0+3];
            red[gq][tt][b] = p;
        }
    }
    __syncthreads();
    if (t < TG*16) {
        int b = t >> 4, tt = t & 15;
        float scv = 0.f;
        #pragma unroll
        for (int gq = 0; gq < 16; gq++) scv += red[gq][tt][b];
        float blk = nb[tt];
        for (int f = 0; f < 64; f++) blk = fmaf(e1s[b][f], nwb[tt*128 + f], blk);
        for (int f = 0; f < 64; f++) blk = fmaf(e2s[b][f], nwb[tt*128 + 64 + f], blk);
        srep[b][tt] = fmaxf(scv + blk, 0.f);
    }
    __syncthreads();
    if (t < TG*16) {
        int b = t >> 4, o = t & 15;
        float a = mb1[o];
        #pragma unroll
        for (int f = 0; f < 16; f++) a = fmaf(srep[b][f], mw1[f*16+o], a);
        s2s[b][o] = fmaxf(a, 0.f);
    }
    __syncthreads();
    if (t < TG) {
        float sco = sb2[0], sm = mb2[0];
        #pragma unroll
        for (int f = 0; f < 16; f++) {
            sco = fmaf(s1s[t][f], sw2[f], sco);
            sm  = fmaf(s2s[t][f], mw2[f], sm);
        }
        float score = 1.f / (1.f + __expf(-sco));
        float sim   = 1.f / (1.f + __expf(-sm));
        out[b0 + t] = alpha[0]*score + beta[0]*sim;
    }
}

// ------------------------------------------------------------------
extern "C" void kernel_launch(void* const* d_in, const int* in_sizes, int n_in,
                              void* d_out, int out_size, void* d_ws, size_t ws_size,
                              hipStream_t stream)
{
    const float* qx  = (const float*)d_in[0];
    const float* cx  = (const float*)d_in[1];
    const int*   qei = (const int*)d_in[2];
    const int*   cei = (const int*)d_in[3];
    const int*   qgi = (const int*)d_in[4];
    const int*   cgi = (const int*)d_in[5];
    const float* Wgw1 = (const float*)d_in[6];
    const float* Wgb1 = (const float*)d_in[7];
    const float* Wgw2 = (const float*)d_in[8];
    const float* Wgb2 = (const float*)d_in[9];
    const float* Wgam = (const float*)d_in[10];
    const float* Wbet = (const float*)d_in[11];
    const float* Weps = (const float*)d_in[12];
    const float* Wiw  = (const float*)d_in[13];
    const float* Wib  = (const float*)d_in[14];
    const float* Wow  = (const float*)d_in[15];
    const float* Wob  = (const float*)d_in[16];
    const float* Wcw1 = (const float*)d_in[17];
    const float* Wcb1 = (const float*)d_in[18];
    const float* Wcw2 = (const float*)d_in[19];
    const float* Wcb2 = (const float*)d_in[20];
    const float* Wsw1 = (const float*)d_in[21];
    const float* Wsb1 = (const float*)d_in[22];
    const float* Wsw2 = (const float*)d_in[23];
    const float* Wsb2 = (const float*)d_in[24];
    const float* Wnw  = (const float*)d_in[25];
    const float* Wnwb = (const float*)d_in[26];
    const float* Wnb  = (const float*)d_in[27];
    const float* Wmw1 = (const float*)d_in[28];
    const float* Wmb1 = (const float*)d_in[29];
    const float* Wmw2 = (const float*)d_in[30];
    const float* Wmb2 = (const float*)d_in[31];
    const float* Wal  = (const float*)d_in[32];
    const float* Wbe  = (const float*)d_in[33];

    float* F = (float*)d_ws;
    unsigned short* bigh = (unsigned short*)F;     // 2NN*64 bf16 = 33.5 MB
    int*   rank   = (int*)F;                       // 2M ints, aliases bigh
    bf16*  xh     = (bf16*)(F + 8388608);          // 2NN*64 bf16 = 33.5 MB
    float* zbuf   = F + 16777216;                  // ZTOTM floats
    float* stats3 = zbuf;                          // 2x3x128 (l*256 + side*128)
    float* pooled3= zbuf + 768;                    // (side*3+l)*BG*64
    float* qf     = F + 16777216 + ZTOTM;          // BG*192
    float* cf     = qf + 196608;                   // BG*192
    int*   rowptr = (int*)(cf + 196608);           // 2NN+1
    int*   cnt    = rowptr + (2*NN + 1);           // 2NN
    int*   col    = cnt + 2*NN;                    // 2M
    int*   bsum   = col + 2*NEDGE;                 // 256
    int*   boff   = bsum + 256;                    // 256
    uintptr_t wtb = (uintptr_t)(boff + 256);
    wtb = (wtb + 63) & ~((uintptr_t)63);
    short* w1h = (short*)wtb;
    short* w1l = w1h + 3*4096;
    short* w2h = w1l + 3*4096;
    short* w2l = w2h + 3*4096;
    short* wih = w2l + 3*4096;
    short* wil = wih + 3*4096;

    k_wprep<<<144, 256, 0, stream>>>(Wgw1, Wgw2, Wiw, w1h, w1l, w2h, w2l, wih, wil);
    k_cvtM  <<<16384, 256, 0, stream>>>(qx, cx, xh, cnt, zbuf);
    k_histM <<<8192, 256, 0, stream>>>(qei, cei, cnt, rank);
    k_scan1M<<<256, 256, 0, stream>>>(cnt, rowptr, bsum);
    k_scan2M<<<1, 256, 0, stream>>>(bsum, boff, rowptr);
    k_scan3M<<<1024, 256, 0, stream>>>(rowptr, boff);
    k_fillM <<<8192, 256, 0, stream>>>(qei, cei, rowptr, rank, col);

    float* pq0 = pooled3;                          // pooled_0 q
    float* pc0 = pooled3 + (size_t)3*BG*64;        // pooled_0 c
    float* pq1 = pooled3 + (size_t)1*BG*64;
    float* pc1 = pooled3 + (size_t)4*BG*64;
    float* pq2 = pooled3 + (size_t)2*BG*64;
    float* pc2 = pooled3 + (size_t)5*BG*64;

    // ---- layer 0 ----
    k_agg_ginM<<<2048, 256, 0, stream>>>(xh, rowptr, col, Weps + 0,
                                         w1h, w1l, Wgb1, w2h, w2l, Wgb2,
                                         bigh, stats3 + 0,
                                         nullptr, nullptr, nullptr,
                                         qgi, cgi, nullptr, nullptr);
    k_bn_apply<<<16384, 256, 0, stream>>>(bigh, stats3 + 0, Wgam, Wbet, xh,
                                          nullptr, nullptr, nullptr, nullptr,
                                          qf, cf, 0);
    // ---- layer 1 (agg also does inner_0 + pool_0) ----
    k_agg_ginM<<<2048, 256, 0, stream>>>(xh, rowptr, col, Weps + 1,
                                         w1h + 4096, w1l + 4096, Wgb1 + 64,
                                         w2h + 4096, w2l + 4096, Wgb2 + 64,
                                         bigh, stats3 + 256,
                                         wih, wil, Wib,
                                         qgi, cgi, pq0, pc0);
    k_bn_apply<<<16384, 256, 0, stream>>>(bigh, stats3 + 256, Wgam + 64, Wbet + 64, xh,
                                          pq0, pc0, Wow, Wob,
                                          qf, cf, 0);
    // ---- layer 2 (agg also does inner_1 + pool_1) ----
    k_agg_ginM<<<2048, 256, 0, stream>>>(xh, rowptr, col, Weps + 2,
                                         w1h + 2*4096, w1l + 2*4096, Wgb1 + 128,
                                         w2h + 2*4096, w2l + 2*4096, Wgb2 + 128,
                                         bigh, stats3 + 512,
                                         wih + 4096, wil + 4096, Wib + 64,
                                         qgi, cgi, pq1, pc1);
    k_bn_innerM<<<2048, 256, 0, stream>>>(bigh, stats3 + 512,
                                          Wgam + 128, Wbet + 128,
                                          wih + 2*4096, wil + 2*4096, Wib + 128,
                                          xh, qgi, cgi, pq2, pc2,
                                          pq1, pc1, Wow + 4096, Wob + 64,
                                          qf, cf, 64);

    k_tailM<<<BG/TG, 256, 0, stream>>>(qf, cf, pq2, pc2,
                                       Wow + 2*4096, Wob + 2*64,
                                       Wcw1, Wcb1, Wcw2, Wcb2,
                                       Wsw1, Wsb1, Wsw2, Wsb2,
                                       Wnw, Wnwb, Wnb, Wmw1, Wmb1, Wmw2, Wmb2,
                                       Wal, Wbe, (float*)d_out);
}